// Round 6
// baseline (209.253 us; speedup 1.0000x reference)
//
#include <hip/hip_runtime.h>
#include <hip/hip_bf16.h>
#include <stdint.h>

// Problem constants (B=2, T=2048, D=2048, H=16, HD=128, ALPHA=1.0)
#define BT    4096
#define DM    2048
#define TSEQ  2048
#define NHEAD 16
#define HD    128
#define QKV_LD 6144
#define ATT_SCALE 0.088388347648318447f   // 128^-0.5
#define WIN   64

typedef __attribute__((ext_vector_type(8))) short short8;
typedef __attribute__((ext_vector_type(4))) float f32x4;

__device__ __forceinline__ uint16_t f2bf(float f) {
  uint32_t u = __float_as_uint(f);
  return (uint16_t)((u + 0x7FFFu + ((u >> 16) & 1u)) >> 16);  // RNE
}

__device__ __forceinline__ void gload_lds16(const void* g, void* l) {
  __builtin_amdgcn_global_load_lds((__attribute__((address_space(1))) void*)g,
                                   (__attribute__((address_space(3))) void*)l,
                                   16, 0, 0);
}

// ---------------- prep: all fp32->bf16 casts + bias concat, one launch ----------------
__global__ __launch_bounds__(256) void prep(const float* __restrict__ x,
                                            const float* __restrict__ qw,
                                            const float* __restrict__ kw,
                                            const float* __restrict__ vw,
                                            const float* __restrict__ ow,
                                            const float* __restrict__ qb,
                                            const float* __restrict__ kb,
                                            const float* __restrict__ vb,
                                            uint16_t* __restrict__ xb,
                                            uint16_t* __restrict__ wqkv,
                                            uint16_t* __restrict__ wo,
                                            float* __restrict__ bcat) {
  const int NX = BT * DM / 4;
  const int NW = DM * DM / 4;
  const int total = NX + 4 * NW;
  int i0 = blockIdx.x * 256 + threadIdx.x;
  for (int idx = i0; idx < total; idx += gridDim.x * 256) {
    const float* src;
    uint16_t* dst;
    int off;
    if (idx < NX)            { src = x;  dst = xb;                          off = idx; }
    else if (idx < NX + NW)  { src = qw; dst = wqkv;                        off = idx - NX; }
    else if (idx < NX + 2*NW){ src = kw; dst = wqkv + (size_t)DM * DM;      off = idx - NX - NW; }
    else if (idx < NX + 3*NW){ src = vw; dst = wqkv + (size_t)2 * DM * DM;  off = idx - NX - 2*NW; }
    else                     { src = ow; dst = wo;                          off = idx - NX - 3*NW; }
    float4 v = ((const float4*)src)[off];
    ushort4 o;
    o.x = f2bf(v.x); o.y = f2bf(v.y); o.z = f2bf(v.z); o.w = f2bf(v.w);
    ((ushort4*)dst)[off] = o;
  }
  if (i0 < 3 * DM) {
    float v = (i0 < DM) ? qb[i0] : (i0 < 2 * DM ? kb[i0 - DM] : vb[i0 - 2 * DM]);
    bcat[i0] = v;
  }
}

// ---------------- 4-deep pipelined 128x128 bf16 GEMM (2 blocks/CU) ----------------
// C[M,N] = A[M,K] @ B[N,K]^T + bias.  BM=BN=128, BK=32, 256 thr = 4 waves (2x2),
// per-wave C = 64x64 (4x4 frags).  LDS 64 KiB = 4 bufs x (A 128x32 + B 128x32)
// -> 2 blocks/CU (16 waves/CU) for TLP latency hiding [m114 mechanism].
// Stage tile t+3 into buf (t-1)&3 (readers provably done) -> race-free [R4-verified].
// Counted vmcnt(8) per tile (2 tiles in flight); drain only in 3-tile peel.
// Chunk swizzle (R4-verified, 0 conflicts): phys chunk = logical ^ ((row>>1)&3).
// XCD-rect: XCD owns a compact (nbm/MB_) x (nbx/(8/MB_)) tile rect [R5-verified FETCH win].
template <int MB_, bool OUT_BF16>
__global__ __launch_bounds__(256, 2) void gemm128(const uint16_t* __restrict__ A,
                                                  const uint16_t* __restrict__ B,
                                                  const float* __restrict__ bias,
                                                  void* __restrict__ Cout,
                                                  int M, int N, int K) {
  __shared__ uint16_t sm[4 * 8192];   // 64 KiB

  const int tid = threadIdx.x;
  const int l   = tid & 63;
  const int wid = tid >> 6;        // 0..3
  const int wr  = wid >> 1;        // 0..1 (M half)
  const int wc  = wid & 1;         // 0..1 (N half)
  const int ln  = l & 15;
  const int g   = l >> 4;          // 0..3 (k-group)

  // XCD-rect mapping
  constexpr int NB_ = 8 / MB_;
  const int nbx    = N >> 7;
  const int nbm    = M >> 7;
  const int bid    = blockIdx.x;
  const int xcd    = bid & 7;
  const int idx    = bid >> 3;
  const int rect_n = nbx / NB_;
  const int rect_m = nbm / MB_;
  const int m_t    = (xcd / NB_) * rect_m + idx / rect_n;
  const int n_t    = (xcd % NB_) * rect_n + idx % rect_n;
  const int m0     = m_t << 7;
  const int n0     = n_t << 7;

  // staging: per-lane global source (pre-swizzled chunk), wave-uniform LDS dst
  const int srow = l >> 2;                       // 0..15
  const int gch  = (l & 3) ^ ((l >> 3) & 3);     // phys chunk for row = wid*16+srow
  const uint16_t* pa0 = A + (size_t)(m0 + wid * 16 + srow) * K + gch * 8;
  const uint16_t* pa1 = pa0 + (size_t)64 * K;
  const uint16_t* pb0 = B + (size_t)(n0 + wid * 16 + srow) * K + gch * 8;
  const uint16_t* pb1 = pb0 + (size_t)64 * K;
  const int la0 = wid * 512;            // elems; buf = A[0,4096) | B[4096,8192)
  const int la1 = 2048 + wid * 512;
  const int lb0 = 4096 + wid * 512;
  const int lb1 = 6144 + wid * 512;

  // read side: physical chunk (row = mult16 + ln -> (row>>1)&3 == (ln>>1)&3)
  const int pc = g ^ ((ln >> 1) & 3);

  f32x4 acc[4][4];
#pragma unroll
  for (int i = 0; i < 4; ++i)
#pragma unroll
    for (int j = 0; j < 4; ++j) acc[i][j] = (f32x4){0.f, 0.f, 0.f, 0.f};

  const int nt = K >> 5;   // 64

#define STAGE(T)                                                        \
  {                                                                     \
    uint16_t* base_ = sm + (size_t)((T) & 3) * 8192;                    \
    const size_t ko_ = (size_t)(T) * 32;                                \
    gload_lds16(pa0 + ko_, base_ + la0);                                \
    gload_lds16(pa1 + ko_, base_ + la1);                                \
    gload_lds16(pb0 + ko_, base_ + lb0);                                \
    gload_lds16(pb1 + ko_, base_ + lb1);                                \
  }

#define COMPUTE(T)                                                      \
  {                                                                     \
    const uint16_t* buf_ = sm + (size_t)((T) & 3) * 8192;               \
    short8 af_[4], bf_[4];                                              \
    _Pragma("unroll")                                                   \
    for (int fi = 0; fi < 4; ++fi)                                      \
      af_[fi] = *(const short8*)(buf_ + (wr * 64 + fi * 16 + ln) * 32 + pc * 8); \
    _Pragma("unroll")                                                   \
    for (int fj = 0; fj < 4; ++fj)                                      \
      bf_[fj] = *(const short8*)(buf_ + 4096 + (wc * 64 + fj * 16 + ln) * 32 + pc * 8); \
    __builtin_amdgcn_s_setprio(1);                                      \
    _Pragma("unroll")                                                   \
    for (int fi = 0; fi < 4; ++fi)                                      \
      _Pragma("unroll")                                                 \
      for (int fj = 0; fj < 4; ++fj)                                    \
        acc[fi][fj] = __builtin_amdgcn_mfma_f32_16x16x32_bf16(          \
            af_[fi], bf_[fj], acc[fi][fj], 0, 0, 0);                    \
    __builtin_amdgcn_s_setprio(0);                                      \
  }

  // prologue: tiles 0,1,2 (12 loads/thread)
  STAGE(0); STAGE(1); STAGE(2);
  asm volatile("s_waitcnt vmcnt(8)" ::: "memory");   // tile 0 landed
  __builtin_amdgcn_s_barrier();

#pragma unroll 1
  for (int t = 0; t < nt - 3; ++t) {
    STAGE(t + 3);                                    // -> buf (t-1)&3: safe
    COMPUTE(t);
    asm volatile("s_waitcnt vmcnt(8)" ::: "memory"); // tile t+1 landed
    __builtin_amdgcn_s_barrier();
  }
  COMPUTE(nt - 3);
  asm volatile("s_waitcnt vmcnt(4)" ::: "memory");
  __builtin_amdgcn_s_barrier();
  COMPUTE(nt - 2);
  asm volatile("s_waitcnt vmcnt(0)" ::: "memory");
  __builtin_amdgcn_s_barrier();
  COMPUTE(nt - 1);
#undef STAGE
#undef COMPUTE

  // epilogue: C/D layout col=lane&15, row=(lane>>4)*4+reg [m89, R2-verified]
  const int g4 = g * 4;
#pragma unroll
  for (int fi = 0; fi < 4; ++fi) {
    size_t row = (size_t)(m0 + wr * 64 + fi * 16 + g4);
#pragma unroll
    for (int fj = 0; fj < 4; ++fj) {
      int col = n0 + wc * 64 + fj * 16 + ln;
      float bv = bias[col];
#pragma unroll
      for (int r = 0; r < 4; ++r) {
        float v = acc[fi][fj][r] + bv;
        if (OUT_BF16) ((uint16_t*)Cout)[(row + r) * N + col] = f2bf(v);
        else          ((float*)Cout)[(row + r) * N + col] = v;
      }
    }
  }
}

// ---------------- MFMA windowed causal attention (unchanged, R2-verified) ----------------
__global__ __launch_bounds__(256) void attn_mfma(const uint16_t* __restrict__ QKV,
                                                 uint16_t* __restrict__ O) {
  __shared__ __align__(16) uint16_t smem[16384 + 17408];
  uint16_t* Qs = smem;
  uint16_t* Vt = smem + 16384;
  uint16_t* Pl = smem;

  const int tid  = threadIdx.x;
  const int lane = tid & 63;
  const int w    = tid >> 6;
  const int g    = lane >> 4;
  const int ln   = lane & 15;

  const int i0 = blockIdx.x * 64;
  const int h  = blockIdx.y;
  const int b  = blockIdx.z;
  const int wb = i0 - 63;
  const size_t hoff  = (size_t)h * HD;
  const size_t bbase = (size_t)b * TSEQ;

#pragma unroll
  for (int it = 0; it < 8; ++it) {
    int s   = it * 256 + tid;
    int row = s >> 4, c = s & 15;
    int j = wb + row;
    if (j >= 0 && j < TSEQ) {
      const uint16_t* gsrc = QKV + (bbase + j) * (size_t)QKV_LD + hoff
                           + (size_t)((c ^ (row & 7)) * 8);
      uint16_t* ldst = Qs + (size_t)(s & ~63) * 8;
      gload_lds16(gsrc, ldst);
    } else {
      uint4 z = {0, 0, 0, 0};
      *(uint4*)(Qs + (size_t)s * 8) = z;
    }
  }

#pragma unroll
  for (int it = 0; it < 4; ++it) {
    int s  = it * 256 + tid;
    int jp = (s & 15) | (it << 4);
    int dc = (s >> 4) & 15;
    int j0 = wb + 2 * jp;
    uint4 va = {0, 0, 0, 0}, vb = {0, 0, 0, 0};
    if (j0 >= 0 && j0 < TSEQ)
      va = *(const uint4*)(QKV + (bbase + j0) * (size_t)QKV_LD + 2 * DM + hoff + dc * 8);
    if (j0 + 1 >= 0 && j0 + 1 < TSEQ)
      vb = *(const uint4*)(QKV + (bbase + j0 + 1) * (size_t)QKV_LD + 2 * DM + hoff + dc * 8);
    const uint16_t* ap = (const uint16_t*)&va;
    const uint16_t* bp = (const uint16_t*)&vb;
#pragma unroll
    for (int t = 0; t < 8; ++t) {
      uint32_t pk = (uint32_t)ap[t] | ((uint32_t)bp[t] << 16);
      *(uint32_t*)(Vt + (size_t)(dc * 8 + t) * 136 + 2 * jp) = pk;
    }
  }

  short8 kreg[4];
  {
    const uint16_t* kp = QKV + (bbase + i0 + w * 16 + ln) * (size_t)QKV_LD
                       + DM + hoff + g * 8;
#pragma unroll
    for (int kc = 0; kc < 4; ++kc) kreg[kc] = *(const short8*)(kp + kc * 32);
  }

  __syncthreads();

  f32x4 acc[8];
#pragma unroll
  for (int nf = 0; nf < 8; ++nf) acc[nf] = (f32x4){0.f, 0.f, 0.f, 0.f};
#pragma unroll
  for (int kc = 0; kc < 4; ++kc) {
#pragma unroll
    for (int nf = 0; nf < 8; ++nf) {
      int row = nf * 16 + ln;
      int chunk = (kc * 4 + g) ^ (row & 7);
      short8 qf = *(const short8*)(Qs + (size_t)row * 128 + chunk * 8);
      acc[nf] = __builtin_amdgcn_mfma_f32_16x16x32_bf16(kreg[kc], qf, acc[nf], 0, 0, 0);
    }
  }

#pragma unroll
  for (int nf = 0; nf < 8; ++nf) {
    int rj = nf * 16 + ln;
    int jg = wb + rj;
#pragma unroll
    for (int r = 0; r < 4; ++r) {
      int il = w * 16 + g * 4 + r;
      int delta = il + 63 - rj;
      float v = acc[nf][r] * ATT_SCALE - (float)delta;
      acc[nf][r] = ((unsigned)delta < 64u && jg >= 0) ? v : -1e30f;
    }
  }

  float inv[4];
#pragma unroll
  for (int r = 0; r < 4; ++r) {
    float mx = acc[0][r];
#pragma unroll
    for (int nf = 1; nf < 8; ++nf) mx = fmaxf(mx, acc[nf][r]);
    mx = fmaxf(mx, __shfl_xor(mx, 1));
    mx = fmaxf(mx, __shfl_xor(mx, 2));
    mx = fmaxf(mx, __shfl_xor(mx, 4));
    mx = fmaxf(mx, __shfl_xor(mx, 8));
    float s = 0.f;
#pragma unroll
    for (int nf = 0; nf < 8; ++nf) {
      float e = __expf(acc[nf][r] - mx);
      acc[nf][r] = e;
      s += e;
    }
    s += __shfl_xor(s, 1);
    s += __shfl_xor(s, 2);
    s += __shfl_xor(s, 4);
    s += __shfl_xor(s, 8);
    inv[r] = 1.0f / s;
  }

  __syncthreads();

#pragma unroll
  for (int nf = 0; nf < 8; ++nf)
#pragma unroll
    for (int r = 0; r < 4; ++r)
      Pl[(size_t)(w * 16 + g * 4 + r) * 136 + nf * 16 + ln] = f2bf(acc[nf][r]);
  asm volatile("s_waitcnt lgkmcnt(0)" ::: "memory");
  __builtin_amdgcn_sched_barrier(0);

  f32x4 o[8];
#pragma unroll
  for (int nf = 0; nf < 8; ++nf) o[nf] = (f32x4){0.f, 0.f, 0.f, 0.f};
#pragma unroll
  for (int kc = 0; kc < 4; ++kc) {
    short8 pa = *(const short8*)(Pl + (size_t)(w * 16 + ln) * 136 + kc * 32 + g * 8);
#pragma unroll
    for (int nf = 0; nf < 8; ++nf) {
      short8 vbf = *(const short8*)(Vt + (size_t)(nf * 16 + ln) * 136 + kc * 32 + g * 8);
      o[nf] = __builtin_amdgcn_mfma_f32_16x16x32_bf16(pa, vbf, o[nf], 0, 0, 0);
    }
  }

  const size_t obase = (bbase + i0 + w * 16) * (size_t)DM + hoff;
#pragma unroll
  for (int nf = 0; nf < 8; ++nf)
#pragma unroll
    for (int r = 0; r < 4; ++r)
      O[obase + (size_t)(g * 4 + r) * DM + nf * 16 + ln] = f2bf(o[nf][r] * inv[r]);
}

// ---------------- launch ----------------
extern "C" void kernel_launch(void* const* d_in, const int* in_sizes, int n_in,
                              void* d_out, int out_size, void* d_ws, size_t ws_size,
                              hipStream_t stream) {
  const float* x   = (const float*)d_in[0];
  const float* q_w = (const float*)d_in[1];
  const float* q_b = (const float*)d_in[2];
  const float* k_w = (const float*)d_in[3];
  const float* k_b = (const float*)d_in[4];
  const float* v_w = (const float*)d_in[5];
  const float* v_b = (const float*)d_in[6];
  const float* o_w = (const float*)d_in[7];
  const float* o_b = (const float*)d_in[8];

  char* ws = (char*)d_ws;
  const size_t XB_BYTES   = (size_t)BT * DM * 2;
  const size_t W_BYTES    = (size_t)DM * DM * 2;
  const size_t WQKV_BYTES = 3 * W_BYTES;

  uint16_t* xb   = (uint16_t*)(ws);
  uint16_t* wqkv = (uint16_t*)(ws + XB_BYTES);
  uint16_t* wo   = (uint16_t*)(ws + XB_BYTES + WQKV_BYTES);
  float*    bcat = (float*)   (ws + XB_BYTES + WQKV_BYTES + W_BYTES);
  uint16_t* QKVb = (uint16_t*)(ws + XB_BYTES + WQKV_BYTES + W_BYTES + 24576);

  prep<<<2048, 256, 0, stream>>>(x, q_w, k_w, v_w, o_w, q_b, k_b, v_b,
                                 xb, wqkv, wo, bcat);

  // fused QKV projection: [4096][2048] @ [6144][2048]^T -> [4096][6144]
  // 32x48 = 1536 blocks = 6/CU balanced; XCD rect 16m x 12n
  gemm128<2, true><<<(BT / 128) * (3 * DM / 128), 256, 0, stream>>>(
      xb, wqkv, bcat, QKVb, BT, 3 * DM, DM);

  dim3 ga(TSEQ / 64, NHEAD, 2);
  attn_mfma<<<ga, 256, 0, stream>>>(QKVb, xb);

  // O projection: 32x16 = 512 blocks = 2/CU balanced; XCD rect 8m x 8n
  gemm128<4, false><<<(BT / 128) * (DM / 128), 256, 0, stream>>>(
      xb, wo, o_b, d_out, BT, DM, DM);
}